// Round 4
// baseline (40.255 us; speedup 1.0000x reference)
//
#include <hip/hip_runtime.h>

#define G 7
#define CCH 256
#define NLVL 6

__device__ __constant__ int kD[NLVL]  = {38, 19, 10, 5, 3, 1};
__device__ __constant__ int kD2[NLVL] = {1444, 361, 100, 25, 9, 1};
// base offset (in floats) of each level inside the transposed fmap buffer
__device__ __constant__ int kBaseT[NLVL + 1] = {0, 369664, 462080, 487680, 494080, 496384, 496640};

#define FMT_TOTAL 496640  // floats

// ---------------- kernel 1: transpose fmaps [C][D*D] -> [D*D][C] ----------------
__global__ __launch_bounds__(256) void transpose_fmaps(
    const float* __restrict__ f0, const float* __restrict__ f1,
    const float* __restrict__ f2, const float* __restrict__ f3,
    const float* __restrict__ f4, const float* __restrict__ f5,
    float* __restrict__ fmT)
{
    int o = blockIdx.x * blockDim.x + threadIdx.x;
    if (o >= FMT_TOTAL) return;
    int l = 0;
#pragma unroll
    for (int k = 1; k < NLVL; ++k) l += (o >= kBaseT[k]);
    int rel = o - kBaseT[l];
    int p = rel >> 8;        // position within D*D
    int c = rel & 255;       // channel
    const float* f;
    switch (l) {
        case 0: f = f0; break;
        case 1: f = f1; break;
        case 2: f = f2; break;
        case 3: f = f3; break;
        case 4: f = f4; break;
        default: f = f5; break;
    }
    fmT[o] = f[c * kD2[l] + p];
}

// ---------------- kernel 2: one block per (box, channel-half) ----------------
__global__ __launch_bounds__(256) void roialign_main(
    const float* __restrict__ boxes, const float* __restrict__ fmT,
    float* __restrict__ out)
{
    __shared__ float sOut[128 * 49];   // 25,088 B: [c_local][g]
    __shared__ float4 sW[49];
    __shared__ int4 sOff[49];

    int b = blockIdx.x;
    int n = b >> 1;
    int chalf = b & 1;
    int tid = threadIdx.x;

    if (tid < 49) {
        float bx1 = boxes[n * 4 + 0];
        float by1 = boxes[n * 4 + 1];
        float bx2 = boxes[n * 4 + 2];
        float by2 = boxes[n * 4 + 3];
        float w = bx2 - bx1;
        float h = by2 - by1;
        // level: clip(floor(5 + log2(sqrt(w*h))), 0, 5), same f32 op order as ref
        float avg = sqrtf(w * h);
        float lf = floorf((float)(NLVL - 1) + log2f(avg));
        lf = fminf(fmaxf(lf, 0.0f), (float)(NLVL - 1));
        int lvl = (int)lf;
        int D = kD[lvl];
        float Dm1 = (float)(D - 1);
        int base = kBaseT[lvl];

        int i = tid / 7;
        int j = tid - i * 7;
        float xr = fminf(fmaxf(bx1 + ((float)i * w) / 6.0f, 0.0f), 1.0f);
        float yr = fminf(fmaxf(by1 + ((float)j * h) / 6.0f, 0.0f), 1.0f);
        float ux = xr * Dm1;
        float uy = yr * Dm1;
        float x0 = floorf(ux);
        float y0 = floorf(uy);
        int ix0 = (int)x0;
        int iy0 = (int)y0;
        float fx = ux - x0;   // px1
        float fy = uy - y0;   // py1
        int ix1 = min(ix0 + 1, D - 1);
        int iy1 = min(iy0 + 1, D - 1);

        sOff[tid] = make_int4(base + (ix0 * D + iy0) * CCH,
                              base + (ix1 * D + iy0) * CCH,
                              base + (ix0 * D + iy1) * CCH,
                              base + (ix1 * D + iy1) * CCH);
        float px0 = 1.0f - fx, py0 = 1.0f - fy;
        sW[tid] = make_float4(px0 * py0, fx * py0, px0 * fy, fx * fy);
    }
    __syncthreads();

    // phase 1: 64 channel-pairs x 4 grid-quarters; float2 loads (512 B/wave-instr)
    int cpair = tid & 63;            // channel pair within this half
    int gq = tid >> 6;               // grid quarter 0..3
    int cloc = cpair * 2;            // 0..126
    int cglob = chalf * 128 + cloc;
    int gBase = gq * 12;

#define BODY(gg)                                                            \
    {                                                                       \
        int g = (gg);                                                       \
        int4 o = sOff[g];                                                   \
        float4 wv = sW[g];                                                  \
        float2 a = *(const float2*)(fmT + o.x + cglob);                     \
        float2 bb = *(const float2*)(fmT + o.y + cglob);                    \
        float2 cc = *(const float2*)(fmT + o.z + cglob);                    \
        float2 dd = *(const float2*)(fmT + o.w + cglob);                    \
        sOut[cloc * 49 + g]       = wv.x * a.x + wv.y * bb.x                \
                                  + wv.z * cc.x + wv.w * dd.x;              \
        sOut[(cloc + 1) * 49 + g] = wv.x * a.y + wv.y * bb.y                \
                                  + wv.z * cc.y + wv.w * dd.y;              \
    }

#pragma unroll
    for (int it = 0; it < 12; ++it) BODY(gBase + it);
    if (gq == 0) BODY(48);           // 49th grid point
#undef BODY
    __syncthreads();

    // phase 2: coalesced float4 writes of this half-box tile (24.5 KB)
    const float4* s4 = (const float4*)sOut;
    float4* out4 = (float4*)(out + (size_t)n * (CCH * G * G) + chalf * (128 * 49));
    for (int q = tid; q < 1568; q += 256) out4[q] = s4[q];
}

// ---------------- fallback (round-2 kernel) if ws too small ----------------
__global__ __launch_bounds__(256) void roialign_fallback(
    const float* __restrict__ boxes,
    const float* __restrict__ f0, const float* __restrict__ f1,
    const float* __restrict__ f2, const float* __restrict__ f3,
    const float* __restrict__ f4, const float* __restrict__ f5,
    float* __restrict__ out, int total4)
{
    int t = blockIdx.x * blockDim.x + threadIdx.x;
    if (t >= total4) return;
    const int perN = CCH * G * G;
    int idx = t * 4;
    int n = idx / perN;
    int rem = idx - n * perN;
    float bx1 = boxes[n * 4 + 0], by1 = boxes[n * 4 + 1];
    float bx2 = boxes[n * 4 + 2], by2 = boxes[n * 4 + 3];
    float w = bx2 - bx1, h = by2 - by1;
    float avg = sqrtf(w * h);
    float lf = floorf((float)(NLVL - 1) + log2f(avg));
    lf = fminf(fmaxf(lf, 0.0f), (float)(NLVL - 1));
    int lvl = (int)lf;
    const float* fm;
    switch (lvl) {
        case 0: fm = f0; break;
        case 1: fm = f1; break;
        case 2: fm = f2; break;
        case 3: fm = f3; break;
        case 4: fm = f4; break;
        default: fm = f5; break;
    }
    int D = kD[lvl];
    float Dm1 = (float)(D - 1);
    float4 res;
    float* rp = &res.x;
#pragma unroll
    for (int k = 0; k < 4; ++k) {
        int e = rem + k;
        int j = e % G;
        int iq = e / G;
        int i = iq % G;
        int c = iq / G;
        float xr = fminf(fmaxf(bx1 + ((float)i * w) / 6.0f, 0.0f), 1.0f);
        float yr = fminf(fmaxf(by1 + ((float)j * h) / 6.0f, 0.0f), 1.0f);
        float ux = xr * Dm1, uy = yr * Dm1;
        float x0 = floorf(ux), y0 = floorf(uy);
        int ix0 = (int)x0, iy0 = (int)y0;
        float fx = ux - x0, fy = uy - y0;
        int ix1 = min(ix0 + 1, D - 1), iy1 = min(iy0 + 1, D - 1);
        const float* p = fm + c * D * D;
        float v00 = p[ix0 * D + iy0], v10 = p[ix1 * D + iy0];
        float v01 = p[ix0 * D + iy1], v11 = p[ix1 * D + iy1];
        float px0 = 1.0f - fx, py0 = 1.0f - fy;
        rp[k] = px0 * py0 * v00 + fx * py0 * v10 + px0 * fy * v01 + fx * fy * v11;
    }
    reinterpret_cast<float4*>(out)[t] = res;
}

extern "C" void kernel_launch(void* const* d_in, const int* in_sizes, int n_in,
                              void* d_out, int out_size, void* d_ws, size_t ws_size,
                              hipStream_t stream) {
    const float* boxes = (const float*)d_in[0];
    const float* f0 = (const float*)d_in[1];
    const float* f1 = (const float*)d_in[2];
    const float* f2 = (const float*)d_in[3];
    const float* f3 = (const float*)d_in[4];
    const float* f4 = (const float*)d_in[5];
    const float* f5 = (const float*)d_in[6];
    float* out = (float*)d_out;
    int N = in_sizes[0] / 4;

    if (ws_size >= (size_t)FMT_TOTAL * sizeof(float)) {
        float* fmT = (float*)d_ws;
        transpose_fmaps<<<(FMT_TOTAL + 255) / 256, 256, 0, stream>>>(
            f0, f1, f2, f3, f4, f5, fmT);
        roialign_main<<<2 * N, 256, 0, stream>>>(boxes, fmT, out);
    } else {
        int total4 = out_size / 4;
        roialign_fallback<<<(total4 + 255) / 256, 256, 0, stream>>>(
            boxes, f0, f1, f2, f3, f4, f5, out, total4);
    }
}

// Round 5
// 34.715 us; speedup vs baseline: 1.1596x; 1.1596x over previous
//
#include <hip/hip_runtime.h>

#define G 7
#define CCH 256
#define NLVL 6

__device__ __constant__ int kD[NLVL]  = {38, 19, 10, 5, 3, 1};
__device__ __constant__ int kD2[NLVL] = {1444, 361, 100, 25, 9, 1};
// base offset (in floats) of each level inside the transposed fmap buffer
__device__ __constant__ int kBaseT[NLVL + 1] = {0, 369664, 462080, 487680, 494080, 496384, 496640};

#define FMT_TOTAL 496640  // floats

// ---------------- kernel 1: transpose fmaps [C][D*D] -> [D*D][C] ----------------
__global__ __launch_bounds__(256) void transpose_fmaps(
    const float* __restrict__ f0, const float* __restrict__ f1,
    const float* __restrict__ f2, const float* __restrict__ f3,
    const float* __restrict__ f4, const float* __restrict__ f5,
    float* __restrict__ fmT)
{
    int o = blockIdx.x * blockDim.x + threadIdx.x;
    if (o >= FMT_TOTAL) return;
    int l = 0;
#pragma unroll
    for (int k = 1; k < NLVL; ++k) l += (o >= kBaseT[k]);
    int rel = o - kBaseT[l];
    int p = rel >> 8;        // position within D*D
    int c = rel & 255;       // channel
    const float* f;
    switch (l) {
        case 0: f = f0; break;
        case 1: f = f1; break;
        case 2: f = f2; break;
        case 3: f = f3; break;
        case 4: f = f4; break;
        default: f = f5; break;
    }
    fmT[o] = f[c * kD2[l] + p];
}

// ---------------- kernel 2: one block per box, wave-autonomous pipeline ----------------
__global__ __launch_bounds__(256) void roialign_main(
    const float* __restrict__ boxes, const float* __restrict__ fmT,
    float* __restrict__ out)
{
    __shared__ float sOut[CCH * 49];   // [c][g] flat; wave w owns floats [w*3136, (w+1)*3136)
    __shared__ float4 sW[49];
    __shared__ int4 sOff[49];

    int n = blockIdx.x;
    int tid = threadIdx.x;

    if (tid < 49) {
        float bx1 = boxes[n * 4 + 0];
        float by1 = boxes[n * 4 + 1];
        float bx2 = boxes[n * 4 + 2];
        float by2 = boxes[n * 4 + 3];
        float w = bx2 - bx1;
        float h = by2 - by1;
        // level: clip(floor(5 + log2(sqrt(w*h))), 0, 5), same f32 op order as ref
        float avg = sqrtf(w * h);
        float lf = floorf((float)(NLVL - 1) + log2f(avg));
        lf = fminf(fmaxf(lf, 0.0f), (float)(NLVL - 1));
        int lvl = (int)lf;
        int D = kD[lvl];
        float Dm1 = (float)(D - 1);
        int base = kBaseT[lvl];

        int i = tid / 7;
        int j = tid - i * 7;
        float xr = fminf(fmaxf(bx1 + ((float)i * w) / 6.0f, 0.0f), 1.0f);
        float yr = fminf(fmaxf(by1 + ((float)j * h) / 6.0f, 0.0f), 1.0f);
        float ux = xr * Dm1;
        float uy = yr * Dm1;
        float x0 = floorf(ux);
        float y0 = floorf(uy);
        int ix0 = (int)x0;
        int iy0 = (int)y0;
        float fx = ux - x0;   // px1
        float fy = uy - y0;   // py1
        int ix1 = min(ix0 + 1, D - 1);
        int iy1 = min(iy0 + 1, D - 1);

        sOff[tid] = make_int4(base + (ix0 * D + iy0) * CCH,
                              base + (ix1 * D + iy0) * CCH,
                              base + (ix0 * D + iy1) * CCH,
                              base + (ix1 * D + iy1) * CCH);
        float px0 = 1.0f - fx, py0 = 1.0f - fy;
        sW[tid] = make_float4(px0 * py0, fx * py0, px0 * fy, fx * fy);
    }
    __syncthreads();   // the ONLY block-wide barrier (tables ready)

    // ---- compute: lane = channel (c == tid); wave fills only its own slab ----
    // LDS write bank = (49*lane) % 32 = permutation -> conflict-free
#pragma unroll 7
    for (int g = 0; g < 49; ++g) {
        int4 o = sOff[g];
        float4 wv = sW[g];
        float v = wv.x * fmT[o.x + tid] + wv.y * fmT[o.y + tid]
                + wv.z * fmT[o.z + tid] + wv.w * fmT[o.w + tid];
        sOut[tid * 49 + g] = v;
    }

    // wave-local DS ordering: our reads below only touch our own wave's slab,
    // written by lanes of this same wave. No __syncthreads needed.
    asm volatile("s_waitcnt lgkmcnt(0)" ::: "memory");
    __builtin_amdgcn_sched_barrier(0);

    // ---- writeback: wave streams its 64-channel slab (784 float4, coalesced) ----
    int wv_id = tid >> 6;
    int lane = tid & 63;
    const float4* s4 = (const float4*)sOut + wv_id * 784;
    float4* out4 = (float4*)(out + (size_t)n * (CCH * G * G)) + wv_id * 784;
#pragma unroll
    for (int k = 0; k < 12; ++k) {
        out4[k * 64 + lane] = s4[k * 64 + lane];
    }
    if (lane < 16) out4[768 + lane] = s4[768 + lane];   // 784 = 12*64 + 16
}

// ---------------- fallback (round-2 kernel) if ws too small ----------------
__global__ __launch_bounds__(256) void roialign_fallback(
    const float* __restrict__ boxes,
    const float* __restrict__ f0, const float* __restrict__ f1,
    const float* __restrict__ f2, const float* __restrict__ f3,
    const float* __restrict__ f4, const float* __restrict__ f5,
    float* __restrict__ out, int total4)
{
    int t = blockIdx.x * blockDim.x + threadIdx.x;
    if (t >= total4) return;
    const int perN = CCH * G * G;
    int idx = t * 4;
    int n = idx / perN;
    int rem = idx - n * perN;
    float bx1 = boxes[n * 4 + 0], by1 = boxes[n * 4 + 1];
    float bx2 = boxes[n * 4 + 2], by2 = boxes[n * 4 + 3];
    float w = bx2 - bx1, h = by2 - by1;
    float avg = sqrtf(w * h);
    float lf = floorf((float)(NLVL - 1) + log2f(avg));
    lf = fminf(fmaxf(lf, 0.0f), (float)(NLVL - 1));
    int lvl = (int)lf;
    const float* fm;
    switch (lvl) {
        case 0: fm = f0; break;
        case 1: fm = f1; break;
        case 2: fm = f2; break;
        case 3: fm = f3; break;
        case 4: fm = f4; break;
        default: fm = f5; break;
    }
    int D = kD[lvl];
    float Dm1 = (float)(D - 1);
    float4 res;
    float* rp = &res.x;
#pragma unroll
    for (int k = 0; k < 4; ++k) {
        int e = rem + k;
        int j = e % G;
        int iq = e / G;
        int i = iq % G;
        int c = iq / G;
        float xr = fminf(fmaxf(bx1 + ((float)i * w) / 6.0f, 0.0f), 1.0f);
        float yr = fminf(fmaxf(by1 + ((float)j * h) / 6.0f, 0.0f), 1.0f);
        float ux = xr * Dm1, uy = yr * Dm1;
        float x0 = floorf(ux), y0 = floorf(uy);
        int ix0 = (int)x0, iy0 = (int)y0;
        float fx = ux - x0, fy = uy - y0;
        int ix1 = min(ix0 + 1, D - 1), iy1 = min(iy0 + 1, D - 1);
        const float* p = fm + c * D * D;
        float v00 = p[ix0 * D + iy0], v10 = p[ix1 * D + iy0];
        float v01 = p[ix0 * D + iy1], v11 = p[ix1 * D + iy1];
        float px0 = 1.0f - fx, py0 = 1.0f - fy;
        rp[k] = px0 * py0 * v00 + fx * py0 * v10 + px0 * fy * v01 + fx * fy * v11;
    }
    reinterpret_cast<float4*>(out)[t] = res;
}

extern "C" void kernel_launch(void* const* d_in, const int* in_sizes, int n_in,
                              void* d_out, int out_size, void* d_ws, size_t ws_size,
                              hipStream_t stream) {
    const float* boxes = (const float*)d_in[0];
    const float* f0 = (const float*)d_in[1];
    const float* f1 = (const float*)d_in[2];
    const float* f2 = (const float*)d_in[3];
    const float* f3 = (const float*)d_in[4];
    const float* f4 = (const float*)d_in[5];
    const float* f5 = (const float*)d_in[6];
    float* out = (float*)d_out;
    int N = in_sizes[0] / 4;

    if (ws_size >= (size_t)FMT_TOTAL * sizeof(float)) {
        float* fmT = (float*)d_ws;
        transpose_fmaps<<<(FMT_TOTAL + 255) / 256, 256, 0, stream>>>(
            f0, f1, f2, f3, f4, f5, fmT);
        roialign_main<<<N, 256, 0, stream>>>(boxes, fmT, out);
    } else {
        int total4 = out_size / 4;
        roialign_fallback<<<(total4 + 255) / 256, 256, 0, stream>>>(
            boxes, f0, f1, f2, f3, f4, f5, out, total4);
    }
}